// Round 16
// baseline (890.861 us; speedup 1.0000x reference)
//
#include <hip/hip_runtime.h>
#include <hip/hip_bf16.h>

#define M_TOTAL 16384
#define KDIM 2048
#define NDIM 2048
#define NEXP 8
#define BM 256
#define BN 128
#define BK 32
#define RT_MAX 71           // 16384/256 + 7 boundary extras
#define CT 16               // 2048/128 col tiles
#define NWG (RT_MAX * CT)   // 1136 = 8 * 142
#define ABUF 16384          // A-only buffer: 256 rows x 64 B

typedef __attribute__((ext_vector_type(8))) __bf16 bf16x8;
typedef __attribute__((ext_vector_type(4))) float f32x4;

__device__ inline int minI(int a, int b) { return a < b ? a : b; }

__device__ inline bf16x8 cvt8(float4 a, float4 b) {
  bf16x8 r;
  r[0] = (__bf16)a.x; r[1] = (__bf16)a.y; r[2] = (__bf16)a.z; r[3] = (__bf16)a.w;
  r[4] = (__bf16)b.x; r[5] = (__bf16)b.y; r[6] = (__bf16)b.z; r[7] = (__bf16)b.w;
  return r;
}

__device__ inline void gload16(const void* g, void* l) {
  __builtin_amdgcn_global_load_lds(
      (const __attribute__((address_space(1))) void*)g,
      (__attribute__((address_space(3))) void*)l, 16, 0, 0);
}

// ---------------- fp32 -> bf16 conversion (x then W) ----------------
__global__ __launch_bounds__(256) void cvt_both(
    const float* __restrict__ x, const float* __restrict__ w,
    bf16x8* __restrict__ xb, bf16x8* __restrict__ wb) {
  const int NX = (M_TOTAL * KDIM) / 8;
  const int NW = (NEXP * NDIM * KDIM) / 8;
  const int stride = gridDim.x * blockDim.x;
  for (int i = blockIdx.x * blockDim.x + threadIdx.x; i < NX + NW; i += stride) {
    const float4* src = (i < NX) ? ((const float4*)x + (size_t)i * 2)
                                 : ((const float4*)w + (size_t)(i - NX) * 2);
    float4 a = src[0], b = src[1];
    bf16x8 c = cvt8(a, b);
    if (i < NX) xb[i] = c; else wb[i - NX] = c;
  }
}

// ---------------- grouped GEMM: 256x128 tile, BK=32.
// KEY CHANGE vs R4-R15 (all ~32% MfmaUtil, LDS+MFMA pipes serialized):
// B-FRAGMENTS LOAD DIRECTLY FROM GLOBAL into registers -- the B-frag pattern
// (row = col0+wc*64+nt*16+fr, 16B at k-chunk fc) is a plain strided load from
// K-major bf16 W; no swizzle needed; per-tile offset t*64B folds into the
// immediate. B-panel (0.5MB) is L1/L2-resident via XCD swizzle. This HALVES
// LDS traffic (A-only: 16KB write + 32KB read per K-tile ~565cyc vs MFMA
// 620cyc) and moves B onto the TA/L1 pipe which overlaps both. B registers
// double-buffer across tiles (bvX/bvY): B(t+1) loads issue at top of tile t,
// consumed next tile (~1500cyc cover). A stays LDS-staged: 3 bufs x 16KB =
// 48KB -> 2 blocks/CU (R14-confirmed).
// vmcnt calendar: tile t issues exactly 6 VMEM ops (4 B-loads + 2 A-stage),
// so clobber-free vmcnt(6) at tile end retires A-stage(t+1) (issued tile t-1)
// regardless of intra-tile scheduling order; barrier publishes buf[(t+1)%3].
// WAR: A-stage(t+2)->buf[(t+2)%3] read in tile t-1, drained pre-barrier(t-1).
// A-swizzle (0 conflicts since R3): phys chunk = c ^ ((row>>1)&3) via
// pre-swizzled per-lane global source column; LDS dest linear.
__global__ __launch_bounds__(512, 4) void moe_gemm_bg(
    const __hip_bfloat16* __restrict__ xb, const __hip_bfloat16* __restrict__ wb,
    const int* __restrict__ ms, float* __restrict__ out) {
  __shared__ __align__(16) char lds[3 * ABUF];

  // bijective XCD swizzle (NWG = 1136 = 8*142)
  const int orig = blockIdx.x;
  const int wg = (orig & 7) * (NWG / 8) + (orig >> 3);
  const int bt = wg >> 4;     // row-tile 0..70
  const int ntile = wg & 15;  // col-tile 0..15

  // ---- map bt -> (expert e, row0, rows) ----
  int sizes[NEXP];
#pragma unroll
  for (int i = 0; i < NEXP; ++i) sizes[i] = ms[i];
  int e = 0, row0 = 0, rows = 0, acc_t = 0, start = 0;
  bool found = false;
#pragma unroll
  for (int i = 0; i < NEXP; ++i) {
    int nt = (sizes[i] + BM - 1) >> 8;
    if (!found && bt < acc_t + nt) {
      found = true; e = i;
      int tt = bt - acc_t;
      row0 = start + tt * BM;
      rows = minI(sizes[i] - tt * BM, BM);
    }
    acc_t += nt; start += sizes[i];
  }
  if (!found) return;

  const int tid = threadIdx.x;
  const int lane = tid & 63;
  const int wave = tid >> 6;
  const int wr = wave >> 1, wc = wave & 1;  // 4M x 2N waves, 64x64 out each
  const int col0 = ntile * BN;

  // ---- A staging: 2 units of 8KB (rows 0-127, rows 128-255);
  // thread -> row rwh = wave*16 + lane>>2, phys chunk lane&3;
  // logical chunk = (lane&3) ^ ((rwh>>1)&3) = (lane&3) ^ ((lane>>3)&3).
  const int rwh = wave * 16 + (lane >> 2);
  const int colel = (((lane & 3) ^ ((lane >> 3) & 3)) << 3);
  const __hip_bfloat16* aS0 = xb + (size_t)minI(row0 + rwh, M_TOTAL - 1) * KDIM + colel;
  const __hip_bfloat16* aS1 = xb + (size_t)minI(row0 + 128 + rwh, M_TOTAL - 1) * KDIM + colel;

  // ---- B direct-from-global fragment bases (no swizzle; t*32 elems added/tile)
  const int fr = lane & 15, fc = lane >> 4;
  const __hip_bfloat16* wbase = wb + (size_t)e * NDIM * KDIM;
  const __hip_bfloat16* bG0 = wbase + (size_t)(col0 + wc * 64 +  0 + fr) * KDIM + fc * 8;
  const __hip_bfloat16* bG1 = wbase + (size_t)(col0 + wc * 64 + 16 + fr) * KDIM + fc * 8;
  const __hip_bfloat16* bG2 = wbase + (size_t)(col0 + wc * 64 + 32 + fr) * KDIM + fc * 8;
  const __hip_bfloat16* bG3 = wbase + (size_t)(col0 + wc * 64 + 48 + fr) * KDIM + fc * 8;

  // ---- A fragment read byte offsets (within a buffer), swizzled ----
  int offA[4];
#pragma unroll
  for (int mt = 0; mt < 4; ++mt) {
    int r = wr * 64 + mt * 16 + fr;
    offA[mt] = r * 64 + ((fc ^ ((r >> 1) & 3)) << 4);
  }

  f32x4 acc[4][4];
  const f32x4 zero = {0.f, 0.f, 0.f, 0.f};
#pragma unroll
  for (int i = 0; i < 4; ++i)
#pragma unroll
    for (int j = 0; j < 4; ++j) acc[i][j] = zero;

  bf16x8 bvX[4], bvY[4];

#define ST2(BI, T) { char* b_ = lds + (BI) * ABUF + wave * 1024; \
    gload16(aS0 + (size_t)(T) * BK, b_); \
    gload16(aS1 + (size_t)(T) * BK, b_ + 8192); }
#define LDB(SET, T) { \
    bv##SET[0] = *(const bf16x8*)(bG0 + (T) * 32); \
    bv##SET[1] = *(const bf16x8*)(bG1 + (T) * 32); \
    bv##SET[2] = *(const bf16x8*)(bG2 + (T) * 32); \
    bv##SET[3] = *(const bf16x8*)(bG3 + (T) * 32); }

// Tile T: load B(T+1) into alternate set, stage A(T+2), read af, MFMA with
// current set, counted wait (retires A(T+1)), barrier (publishes buf[(T+1)%3]).
#define TILE(T, BR, BI2, CUR, NXT, DOB, DOA, VM) { \
    if (DOB) LDB(NXT, (T) + 1); \
    if (DOA) ST2(BI2, (T) + 2); \
    const char* bb_ = lds + (BR) * ABUF; \
    bf16x8 af[4]; \
    _Pragma("unroll") for (int mt = 0; mt < 4; ++mt) \
      af[mt] = *(const bf16x8*)(bb_ + offA[mt]); \
    __builtin_amdgcn_s_setprio(1); \
    _Pragma("unroll") for (int nt = 0; nt < 4; ++nt) \
      _Pragma("unroll") for (int mt = 0; mt < 4; ++mt) \
        acc[mt][nt] = __builtin_amdgcn_mfma_f32_16x16x32_bf16( \
            af[mt], bv##CUR[nt], acc[mt][nt], 0, 0, 0); \
    __builtin_amdgcn_s_setprio(0); \
    asm volatile("s_waitcnt " VM); \
    __builtin_amdgcn_s_barrier(); \
  }

  // prologue: stage A(0),A(1); load B(0); vmcnt(6) retires A(0); publish buf0.
  ST2(0, 0)
  ST2(1, 1)
  LDB(X, 0)
  asm volatile("s_waitcnt vmcnt(6)");
  __builtin_amdgcn_s_barrier();

  for (int i = 0; i < 10; ++i) {
    const int t = 6 * i;
    TILE(t,     0, 2, X, Y, true, true, "vmcnt(6)")
    TILE(t + 1, 1, 0, Y, X, true, true, "vmcnt(6)")
    TILE(t + 2, 2, 1, X, Y, true, true, "vmcnt(6)")
    TILE(t + 3, 0, 2, Y, X, true, true, "vmcnt(6)")
    TILE(t + 4, 1, 0, X, Y, true, true, "vmcnt(6)")
    TILE(t + 5, 2, 1, Y, X, true, true, "vmcnt(6)")
  }
  TILE(60, 0, 2, X, Y, true,  true,  "vmcnt(6)")  // stages A(62)->buf2
  TILE(61, 1, 0, Y, X, true,  true,  "vmcnt(6)")  // stages A(63)->buf0
  TILE(62, 2, 0, X, Y, true,  false, "vmcnt(4)")  // retires A(63); B(63) in flight
  TILE(63, 0, 0, Y, X, false, false, "vmcnt(0)")  // nothing outstanding

#undef TILE
#undef LDB
#undef ST2

  // ---- epilogue: C/D layout col=lane&15, row=(lane>>4)*4+j ----
  const int er = (lane >> 4) * 4;
#pragma unroll
  for (int mt = 0; mt < 4; ++mt) {
#pragma unroll
    for (int j = 0; j < 4; ++j) {
      int r = wr * 64 + mt * 16 + er + j;
      if (r < rows) {
        float* op = out + (size_t)(row0 + r) * NDIM + col0 + wc * 64 + (lane & 15);
#pragma unroll
        for (int nt = 0; nt < 4; ++nt) op[nt * 16] = acc[mt][nt][j];
      }
    }
  }
}

// ---------------- fallback: direct fp32, reg-staged ----------------
__global__ __launch_bounds__(256) void moe_gemm_f32(
    const float* __restrict__ x, const float* __restrict__ w,
    const int* __restrict__ ms, float* __restrict__ out) {
  __shared__ __align__(16) char As[128 * 64 * 2];
  __shared__ __align__(16) char Bs[128 * 64 * 2];
  int sizes[NEXP];
#pragma unroll
  for (int i = 0; i < NEXP; ++i) sizes[i] = ms[i];
  const int bt = blockIdx.y;
  int e = 0, row0 = 0, rows = 0, acc_t = 0, start = 0;
  bool found = false;
#pragma unroll
  for (int i = 0; i < NEXP; ++i) {
    int nt = (sizes[i] + 127) >> 7;
    if (!found && bt < acc_t + nt) {
      found = true; e = i;
      int tt = bt - acc_t;
      row0 = start + tt * 128;
      rows = minI(sizes[i] - tt * 128, 128);
    }
    acc_t += nt; start += sizes[i];
  }
  if (!found) return;
  const int tid = threadIdx.x;
  const int lane = tid & 63;
  const int wave = tid >> 6;
  const int wm = wave >> 1, wn = wave & 1;
  const int col0 = blockIdx.x * 128;
  const float* wbase = w + (size_t)e * (size_t)NDIM * KDIM;
  const int sr = tid >> 1;
  const int sh = tid & 1;
  const float* aptr = x + (size_t)(row0 + sr) * KDIM + sh * 32;
  const float* bptr = wbase + (size_t)(col0 + sr) * KDIM + sh * 32;
  const bool aval = (sr < rows);
  f32x4 acc[4][4];
  const f32x4 zero = {0.f, 0.f, 0.f, 0.f};
#pragma unroll
  for (int i = 0; i < 4; ++i)
#pragma unroll
    for (int j = 0; j < 4; ++j) acc[i][j] = zero;
  for (int kb = 0; kb < KDIM / 64; ++kb) {
    {
      float4 v[8];
      if (aval) {
        const float4* p = (const float4*)(aptr + kb * 64);
#pragma unroll
        for (int j = 0; j < 8; ++j) v[j] = p[j];
      } else {
#pragma unroll
        for (int j = 0; j < 8; ++j) v[j] = make_float4(0.f, 0.f, 0.f, 0.f);
      }
#pragma unroll
      for (int j = 0; j < 4; ++j) {
        bf16x8 c = cvt8(v[2 * j], v[2 * j + 1]);
        int chunk = (sh * 4 + j) ^ (sr & 7);
        *(bf16x8*)(As + sr * 128 + chunk * 16) = c;
      }
    }
    {
      const float4* p = (const float4*)(bptr + kb * 64);
      float4 u[8];
#pragma unroll
      for (int j = 0; j < 8; ++j) u[j] = p[j];
#pragma unroll
      for (int j = 0; j < 4; ++j) {
        bf16x8 c = cvt8(u[2 * j], u[2 * j + 1]);
        int chunk = (sh * 4 + j) ^ (sr & 7);
        *(bf16x8*)(Bs + sr * 128 + chunk * 16) = c;
      }
    }
    __syncthreads();
#pragma unroll
    for (int ks = 0; ks < 2; ++ks) {
      bf16x8 afr[4], bfv[4];
#pragma unroll
      for (int mt = 0; mt < 4; ++mt) {
        int r = wm * 64 + mt * 16 + (lane & 15);
        int chunk = (ks * 4 + (lane >> 4)) ^ (r & 7);
        afr[mt] = *(const bf16x8*)(As + r * 128 + chunk * 16);
      }
#pragma unroll
      for (int nt = 0; nt < 4; ++nt) {
        int r = wn * 64 + nt * 16 + (lane & 15);
        int chunk = (ks * 4 + (lane >> 4)) ^ (r & 7);
        bfv[nt] = *(const bf16x8*)(Bs + r * 128 + chunk * 16);
      }
#pragma unroll
      for (int mt = 0; mt < 4; ++mt)
#pragma unroll
        for (int nt = 0; nt < 4; ++nt)
          acc[mt][nt] = __builtin_amdgcn_mfma_f32_16x16x32_bf16(
              afr[mt], bfv[nt], acc[mt][nt], 0, 0, 0);
    }
    __syncthreads();
  }
#pragma unroll
  for (int mt = 0; mt < 4; ++mt) {
#pragma unroll
    for (int j = 0; j < 4; ++j) {
      int r = wm * 64 + mt * 16 + (lane >> 4) * 4 + j;
      if (r < rows) {
        float* op = out + (size_t)(row0 + r) * NDIM + col0 + wn * 64 + (lane & 15);
#pragma unroll
        for (int nt = 0; nt < 4; ++nt) op[nt * 16] = acc[mt][nt][j];
      }
    }
  }
}

extern "C" void kernel_launch(void* const* d_in, const int* in_sizes, int n_in,
                              void* d_out, int out_size, void* d_ws, size_t ws_size,
                              hipStream_t stream) {
  const float* x = (const float*)d_in[0];
  const float* w = (const float*)d_in[1];
  const int* ms = (const int*)d_in[2];
  float* out = (float*)d_out;
  const size_t nx = (size_t)M_TOTAL * KDIM;
  const size_t nw = (size_t)NEXP * NDIM * KDIM;
  const size_t need = (nx + nw) * sizeof(__hip_bfloat16);
  if (ws_size >= need) {
    __hip_bfloat16* xb = (__hip_bfloat16*)d_ws;
    __hip_bfloat16* wb = xb + nx;
    cvt_both<<<2048, 256, 0, stream>>>(x, w, (bf16x8*)xb, (bf16x8*)wb);
    moe_gemm_bg<<<dim3(NWG), dim3(512), 0, stream>>>(xb, wb, ms, out);
  } else {
    moe_gemm_f32<<<dim3(16, 135), dim3(256), 0, stream>>>(x, w, ms, out);
  }
}

// Round 17
// 298.133 us; speedup vs baseline: 2.9881x; 2.9881x over previous
//
#include <hip/hip_runtime.h>
#include <hip/hip_bf16.h>

#define M_TOTAL 16384
#define KDIM 2048
#define NDIM 2048
#define NEXP 8
#define BM 256
#define BN 128
#define RT_MAX 71            // 16384/256 + 7 boundary extras
#define CT 16                // 2048/128 col tiles
#define NWG (RT_MAX * CT)    // 1136 = 8 * 142
#define A_UNITS (RT_MAX * 16 * 64 * 64)  // 4,653,056 16B-frag-units
#define W_UNITS (NEXP * 128 * 64 * 64)   // 4,194,304

typedef __attribute__((ext_vector_type(8))) __bf16 bf16x8;
typedef __attribute__((ext_vector_type(4))) float f32x4;

__device__ inline int minI(int a, int b) { return a < b ? a : b; }

__device__ inline bf16x8 cvt8(float4 a, float4 b) {
  bf16x8 r;
  r[0] = (__bf16)a.x; r[1] = (__bf16)a.y; r[2] = (__bf16)a.z; r[3] = (__bf16)a.w;
  r[4] = (__bf16)b.x; r[5] = (__bf16)b.y; r[6] = (__bf16)b.z; r[7] = (__bf16)b.w;
  return r;
}

// ---------------- fp32 -> bf16 FRAGMENT-PACK (replaces cvt) ----------------
// xp layout: unit i = ((bt*16 + m16)*64 + t)*64 + l  (16B per unit)
//   holds x[row0(bt) + m16*16 + (l&15)][t*32 + (l>>4)*8 .. +8] as bf16x8.
// wp layout: unit v = (((e*128 + c16)*64 + t)*64 + l)
//   holds w[e][c16*16 + (l&15)][t*32 + (l>>4)*8 .. +8].
// A wave's MFMA fragment = one contiguous 1KB block (lane l at l*16):
// GEMM reads are fully coalesced. Source reads here are 16 rows x 128B
// (full 64B sectors, near-BW).
__global__ __launch_bounds__(256) void pack_ops(
    const float* __restrict__ x, const float* __restrict__ w,
    const int* __restrict__ ms, bf16x8* __restrict__ xp, bf16x8* __restrict__ wp) {
  const int total = A_UNITS + W_UNITS;
  const int stride = gridDim.x * blockDim.x;
  for (int i = blockIdx.x * blockDim.x + threadIdx.x; i < total; i += stride) {
    if (i < A_UNITS) {
      const int l = i & 63;
      const int t = (i >> 6) & 63;
      const int m16 = (i >> 12) & 15;
      const int bt = i >> 16;
      // expert scan (identical to GEMM's)
      int row0 = 0, acc_t = 0, start = 0;
      bool found = false;
#pragma unroll
      for (int q = 0; q < NEXP; ++q) {
        int sz = ms[q];
        int nt = (sz + BM - 1) >> 8;
        if (!found && bt < acc_t + nt) {
          found = true;
          row0 = start + (bt - acc_t) * BM;
        }
        acc_t += nt; start += sz;
      }
      if (!found) continue;
      const int row = minI(row0 + m16 * 16 + (l & 15), M_TOTAL - 1);
      const int k = t * 32 + (l >> 4) * 8;
      const float4* s = (const float4*)(x + (size_t)row * KDIM + k);
      xp[i] = cvt8(s[0], s[1]);
    } else {
      const int v = i - A_UNITS;
      const int l = v & 63;
      const int t = (v >> 6) & 63;
      const int c16 = (v >> 12) & 127;
      const int e = v >> 19;
      const int col = c16 * 16 + (l & 15);
      const int k = t * 32 + (l >> 4) * 8;
      const float4* s = (const float4*)(w + ((size_t)e * NDIM + col) * KDIM + k);
      wp[v] = cvt8(s[0], s[1]);
    }
  }
}

// ---------------- grouped GEMM: LDS-FREE STREAMING from fragment-packed ops.
// Diagnosis R4-R15: per-CU time = LDS-pipe time + MFMA time (serialized sum;
// R14's 2-block co-residency packed that sum to 94%) -- the LDS pipe itself
// is the serializer. This kernel removes LDS entirely: af/bv fragments load
// directly from xp/wp as coalesced 16B/lane (1KB/wave) global reads, which
// return on the VMEM pipe and overlap MFMA. No barriers, no waitcnts, no
// setprio -- waves free-run, compiler pipelines loads across K-tiles.
// A panel (1MB) shared by 16 XCD-contiguous blocks -> L2-resident; B panel
// 0.5MB -> L1/L2. R16's failure mode (per-lane 4KB-strided B reads) is fixed
// by the pack layout, not by staging.
__global__ __launch_bounds__(512, 2) void moe_gemm_st(
    const __hip_bfloat16* __restrict__ xp, const __hip_bfloat16* __restrict__ wp,
    const int* __restrict__ ms, float* __restrict__ out) {
  // bijective XCD swizzle (NWG = 1136 = 8*142); col-tiles contiguous per XCD
  const int orig = blockIdx.x;
  const int wg = (orig & 7) * (NWG / 8) + (orig >> 3);
  const int bt = wg >> 4;     // row-tile 0..70
  const int ntile = wg & 15;  // col-tile 0..15

  // ---- map bt -> (expert e, row0, rows) ----
  int sizes[NEXP];
#pragma unroll
  for (int i = 0; i < NEXP; ++i) sizes[i] = ms[i];
  int e = 0, row0 = 0, rows = 0, acc_t = 0, start = 0;
  bool found = false;
#pragma unroll
  for (int i = 0; i < NEXP; ++i) {
    int nt = (sizes[i] + BM - 1) >> 8;
    if (!found && bt < acc_t + nt) {
      found = true; e = i;
      int tt = bt - acc_t;
      row0 = start + tt * BM;
      rows = minI(sizes[i] - tt * BM, BM);
    }
    acc_t += nt; start += sizes[i];
  }
  if (!found) return;

  const int tid = threadIdx.x;
  const int lane = tid & 63;
  const int wave = tid >> 6;
  const int wr = wave >> 1, wc = wave & 1;  // 4M x 2N waves, 64x64 out each
  const int col0 = ntile * BN;

  // fragment base pointers (byte arithmetic); per-tile step = 1024 B
  const char* aB = (const char*)xp + ((size_t)bt << 20) +
                   (size_t)(wr * 4) * 65536 + lane * 16;
  const char* bB = (const char*)wp + ((size_t)e << 23) +
                   (size_t)(ntile * 8 + wc * 4) * 65536 + lane * 16;

  f32x4 acc[4][4];
  const f32x4 zero = {0.f, 0.f, 0.f, 0.f};
#pragma unroll
  for (int i = 0; i < 4; ++i)
#pragma unroll
    for (int j = 0; j < 4; ++j) acc[i][j] = zero;

#pragma unroll 4
  for (int t = 0; t < 64; ++t) {
    bf16x8 af[4], bv[4];
#pragma unroll
    for (int mt = 0; mt < 4; ++mt)
      af[mt] = *(const bf16x8*)(aB + mt * 65536 + t * 1024);
#pragma unroll
    for (int nt = 0; nt < 4; ++nt)
      bv[nt] = *(const bf16x8*)(bB + nt * 65536 + t * 1024);
#pragma unroll
    for (int nt = 0; nt < 4; ++nt)
#pragma unroll
      for (int mt = 0; mt < 4; ++mt)
        acc[mt][nt] = __builtin_amdgcn_mfma_f32_16x16x32_bf16(
            af[mt], bv[nt], acc[mt][nt], 0, 0, 0);
  }

  // ---- epilogue: C/D layout col=lane&15, row=(lane>>4)*4+j ----
  const int er = (lane >> 4) * 4;
#pragma unroll
  for (int mt = 0; mt < 4; ++mt) {
#pragma unroll
    for (int j = 0; j < 4; ++j) {
      int r = wr * 64 + mt * 16 + er + j;
      if (r < rows) {
        float* op = out + (size_t)(row0 + r) * NDIM + col0 + wc * 64 + (lane & 15);
#pragma unroll
        for (int nt = 0; nt < 4; ++nt) op[nt * 16] = acc[mt][nt][j];
      }
    }
  }
}

// ---------------- fallback: direct fp32, reg-staged ----------------
__global__ __launch_bounds__(256) void moe_gemm_f32(
    const float* __restrict__ x, const float* __restrict__ w,
    const int* __restrict__ ms, float* __restrict__ out) {
  __shared__ __align__(16) char As[128 * 64 * 2];
  __shared__ __align__(16) char Bs[128 * 64 * 2];
  int sizes[NEXP];
#pragma unroll
  for (int i = 0; i < NEXP; ++i) sizes[i] = ms[i];
  const int bt = blockIdx.y;
  int e = 0, row0 = 0, rows = 0, acc_t = 0, start = 0;
  bool found = false;
#pragma unroll
  for (int i = 0; i < NEXP; ++i) {
    int nt = (sizes[i] + 127) >> 7;
    if (!found && bt < acc_t + nt) {
      found = true; e = i;
      int tt = bt - acc_t;
      row0 = start + tt * 128;
      rows = minI(sizes[i] - tt * 128, 128);
    }
    acc_t += nt; start += sizes[i];
  }
  if (!found) return;
  const int tid = threadIdx.x;
  const int lane = tid & 63;
  const int wave = tid >> 6;
  const int wm = wave >> 1, wn = wave & 1;
  const int col0 = blockIdx.x * 128;
  const float* wbase = w + (size_t)e * (size_t)NDIM * KDIM;
  const int sr = tid >> 1;
  const int sh = tid & 1;
  const float* aptr = x + (size_t)(row0 + sr) * KDIM + sh * 32;
  const float* bptr = wbase + (size_t)(col0 + sr) * KDIM + sh * 32;
  const bool aval = (sr < rows);
  f32x4 acc[4][4];
  const f32x4 zero = {0.f, 0.f, 0.f, 0.f};
#pragma unroll
  for (int i = 0; i < 4; ++i)
#pragma unroll
    for (int j = 0; j < 4; ++j) acc[i][j] = zero;
  for (int kb = 0; kb < KDIM / 64; ++kb) {
    {
      float4 v[8];
      if (aval) {
        const float4* p = (const float4*)(aptr + kb * 64);
#pragma unroll
        for (int j = 0; j < 8; ++j) v[j] = p[j];
      } else {
#pragma unroll
        for (int j = 0; j < 8; ++j) v[j] = make_float4(0.f, 0.f, 0.f, 0.f);
      }
#pragma unroll
      for (int j = 0; j < 4; ++j) {
        bf16x8 c = cvt8(v[2 * j], v[2 * j + 1]);
        int chunk = (sh * 4 + j) ^ (sr & 7);
        *(bf16x8*)(As + sr * 128 + chunk * 16) = c;
      }
    }
    {
      const float4* p = (const float4*)(bptr + kb * 64);
      float4 u[8];
#pragma unroll
      for (int j = 0; j < 8; ++j) u[j] = p[j];
#pragma unroll
      for (int j = 0; j < 4; ++j) {
        bf16x8 c = cvt8(u[2 * j], u[2 * j + 1]);
        int chunk = (sh * 4 + j) ^ (sr & 7);
        *(bf16x8*)(Bs + sr * 128 + chunk * 16) = c;
      }
    }
    __syncthreads();
#pragma unroll
    for (int ks = 0; ks < 2; ++ks) {
      bf16x8 afr[4], bfv[4];
#pragma unroll
      for (int mt = 0; mt < 4; ++mt) {
        int r = wm * 64 + mt * 16 + (lane & 15);
        int chunk = (ks * 4 + (lane >> 4)) ^ (r & 7);
        afr[mt] = *(const bf16x8*)(As + r * 128 + chunk * 16);
      }
#pragma unroll
      for (int nt = 0; nt < 4; ++nt) {
        int r = wn * 64 + nt * 16 + (lane & 15);
        int chunk = (ks * 4 + (lane >> 4)) ^ (r & 7);
        bfv[nt] = *(const bf16x8*)(Bs + r * 128 + chunk * 16);
      }
#pragma unroll
      for (int mt = 0; mt < 4; ++mt)
#pragma unroll
        for (int nt = 0; nt < 4; ++nt)
          acc[mt][nt] = __builtin_amdgcn_mfma_f32_16x16x32_bf16(
              afr[mt], bfv[nt], acc[mt][nt], 0, 0, 0);
    }
    __syncthreads();
  }
#pragma unroll
  for (int mt = 0; mt < 4; ++mt) {
#pragma unroll
    for (int j = 0; j < 4; ++j) {
      int r = wm * 64 + mt * 16 + (lane >> 4) * 4 + j;
      if (r < rows) {
        float* op = out + (size_t)(row0 + r) * NDIM + col0 + wn * 64 + (lane & 15);
#pragma unroll
        for (int nt = 0; nt < 4; ++nt) op[nt * 16] = acc[mt][nt][j];
      }
    }
  }
}

extern "C" void kernel_launch(void* const* d_in, const int* in_sizes, int n_in,
                              void* d_out, int out_size, void* d_ws, size_t ws_size,
                              hipStream_t stream) {
  const float* x = (const float*)d_in[0];
  const float* w = (const float*)d_in[1];
  const int* ms = (const int*)d_in[2];
  float* out = (float*)d_out;
  const size_t need = ((size_t)A_UNITS + W_UNITS) * 16;
  if (ws_size >= need) {
    bf16x8* xp = (bf16x8*)d_ws;
    bf16x8* wp = xp + A_UNITS;
    pack_ops<<<4096, 256, 0, stream>>>(x, w, ms, xp, wp);
    moe_gemm_st<<<dim3(NWG), dim3(512), 0, stream>>>(
        (const __hip_bfloat16*)xp, (const __hip_bfloat16*)wp, ms, out);
  } else {
    moe_gemm_f32<<<dim3(16, 135), dim3(256), 0, stream>>>(x, w, ms, out);
  }
}